// Round 4
// baseline (146.988 us; speedup 1.0000x reference)
//
#include <hip/hip_runtime.h>
#include <math.h>
#include <float.h>

// Problem constants (match reference)
constexpr int Bn  = 64;
constexpr int ICn = 2;
constexpr int OCn = 32;
constexpr int Kn  = 5;
constexpr int Ln  = 65536;
constexpr float FSc = 50000000.0f;
constexpr int JMAXn = 16;

// Conv: grid-stride sweep, fill-style. 2048 blocks x 256 thr = 524288 threads.
// Each thread owns one float4-group of a (b-)slice; stride = one full sample
// (OCn*Ln = 2,097,152 floats), so iteration i processes exactly b = i.
constexpr int TPB    = 256;
constexpr int NBLK   = 2048;
constexpr int SLICE  = OCn * Ln;          // floats per b in y

typedef float f32x4 __attribute__((ext_vector_type(4)));

// ---------------------------------------------------------------------------
// Kernel 1: per-sample steerable weight generation (unchanged, negligible).
// ---------------------------------------------------------------------------
__global__ __launch_bounds__(64) void wgen_kernel(const int* __restrict__ z,
                                                  const float* __restrict__ s,
                                                  const float* __restrict__ w0,
                                                  float* __restrict__ w) {
    const int b  = blockIdx.x;
    const int oc = threadIdx.x;
    if (oc >= OCn) return;

    float pv[5];
#pragma unroll
    for (int c = 0; c < 5; ++c) {
        float v = s[b * 5 + c];
        if (isnan(v)) v = 0.0f;
        else if (isinf(v)) v = (v > 0.0f) ? FLT_MAX : -FLT_MAX;
        pv[c] = v;
    }
    const float neutral[5] = {0.0f, 1.0f, 1.0f, 0.0f, 0.0f};
#pragma unroll
    for (int c = 0; c < 5; ++c) {
        if (!(z[b * 5 + c] > 0)) pv[c] = neutral[c];
    }
    const float f0    = pv[0];
    const float alpha = pv[1];
    const float rho   = pv[2];
    const float a     = pv[4];

    float nw = rintf(5.0f / fmaxf(alpha, 0.001f));
    int new_W = (int)nw;
    if (new_W < 1) new_W = 1;
    if (new_W > JMAXn) new_W = JMAXn;
    const float nWf = (float)new_W;

    float M[Kn][Kn];
#pragma unroll
    for (int xi = 0; xi < Kn; ++xi)
#pragma unroll
        for (int y = 0; y < Kn; ++y) M[xi][y] = 0.0f;

#pragma unroll
    for (int xi = 0; xi < Kn; ++xi) {
        const float src2 = fmaxf((xi + 0.5f) * nWf / 5.0f - 0.5f, 0.0f);
        const int   j0   = (int)floorf(src2);
        const int   j1   = min(j0 + 1, new_W - 1);
        const float lam2 = src2 - (float)j0;
        const int   jj[2] = {j0, j1};
        const float cf[2] = {1.0f - lam2, lam2};
#pragma unroll
        for (int t = 0; t < 2; ++t) {
            const int   j  = jj[t];
            const float cc = cf[t];
            const float src1 = fmaxf((j + 0.5f) * 5.0f / nWf - 0.5f, 0.0f);
            const int   i0   = (int)floorf(src1);
            const int   i1   = min(i0 + 1, Kn - 1);
            const float lam1 = src1 - (float)i0;
#pragma unroll
            for (int y = 0; y < Kn; ++y) {
                const float e = ((y == i0) ? (1.0f - lam1) : 0.0f) +
                                ((y == i1) ? lam1 : 0.0f);
                M[xi][y] += cc * e;
            }
        }
    }

    const float* w0b = w0 + oc * (ICn * Kn);
    float wI[Kn], wQ[Kn];
#pragma unroll
    for (int xi = 0; xi < Kn; ++xi) {
        float aI = 0.0f, aQ = 0.0f;
#pragma unroll
        for (int y = 0; y < Kn; ++y) {
            aI += M[xi][y] * w0b[y];
            aQ += M[xi][y] * w0b[Kn + y];
        }
        wI[xi] = aI;
        wQ[xi] = aQ;
    }

    const float c2pi = (float)(2.0 * M_PI);
    const float cpi  = (float)M_PI;
#pragma unroll
    for (int n = 0; n < Kn; ++n) {
        const float nf  = (float)n;
        const float ph1 = ((c2pi * f0) * nf) / FSc;
        const float c1 = cosf(ph1), s1 = sinf(ph1);
        float I = wI[n], Q = wQ[n];
        float I2 = I * c1 - Q * s1;
        float Q2 = I * s1 + Q * c1;
        const float t   = nf / FSc;
        const float ph2 = (cpi * a) * (t * t);
        const float c2 = cosf(ph2), s2 = sinf(ph2);
        float I3 = I2 * c2 - Q2 * s2;
        float Q3 = I2 * s2 + Q2 * c2;
        wI[n] = rho * I3;
        wQ[n] = rho * Q3;
    }

    float* wb = w + (b * OCn + oc) * (ICn * Kn);
#pragma unroll
    for (int k = 0; k < Kn; ++k) {
        wb[k]      = wI[k];
        wb[Kn + k] = wQ[k];
    }
}

// ---------------------------------------------------------------------------
// Kernel 2: grouped conv1d as a fill-style grid-stride sweep.
// Thread t owns fixed (oc, l0) = (t*4 / L, t*4 % L); iteration i handles
// sample b = i. Instantaneous write window = 8 MB contiguous, moving
// linearly through y — mimics fillBufferAligned (6.7 TB/s measured).
// Weights wave-uniform via readfirstlane; x[b] slice (512 KB) L2/L3-served.
// ---------------------------------------------------------------------------
__global__ __launch_bounds__(TPB) void conv_kernel(const float* __restrict__ x,
                                                   const float* __restrict__ w,
                                                   float* __restrict__ y) {
    const int t  = (int)blockIdx.x * TPB + (int)threadIdx.x;
    const int f0 = t * 4;                 // flat float offset within one b-slice
    const int oc = f0 >> 16;              // f0 / Ln
    const int l0 = f0 & (Ln - 1);         // f0 % Ln
    const int oc_u = __builtin_amdgcn_readfirstlane(oc);  // wave-uniform

    const bool fast = (l0 >= 4) && (l0 + 8 <= Ln);

    const float* xrow = x;                // advances by IC*Ln per iteration
    float*       yrow = y + f0;           // advances by SLICE per iteration

    for (int b = 0; b < Bn; ++b) {
        // 10 wave-uniform weights for (b, oc)
        const float* wo = w + (size_t)(b * OCn + oc_u) * (ICn * Kn);
        float wv[ICn * Kn];
#pragma unroll
        for (int i = 0; i < ICn * Kn; ++i) wv[i] = wo[i];

        const float* x0 = xrow;           // ic = 0
        const float* x1 = xrow + Ln;      // ic = 1

        // window x[l0-4 .. l0+8): 12 floats/ic; used x[l0-2 .. l0+6)
        float xa[12], xc[12];
        if (fast) {
#pragma unroll
            for (int q = 0; q < 3; ++q) {
                const float4 va = *reinterpret_cast<const float4*>(x0 + l0 - 4 + 4 * q);
                const float4 vb = *reinterpret_cast<const float4*>(x1 + l0 - 4 + 4 * q);
                xa[4 * q + 0] = va.x; xa[4 * q + 1] = va.y;
                xa[4 * q + 2] = va.z; xa[4 * q + 3] = va.w;
                xc[4 * q + 0] = vb.x; xc[4 * q + 1] = vb.y;
                xc[4 * q + 2] = vb.z; xc[4 * q + 3] = vb.w;
            }
        } else {
#pragma unroll
            for (int m = 0; m < 12; ++m) {
                const int g = l0 - 4 + m;
                const bool ok = (g >= 0 && g < Ln);
                xa[m] = ok ? x0[g] : 0.0f;
                xc[m] = ok ? x1[g] : 0.0f;
            }
        }

        float a0 = 0.0f, a1 = 0.0f, a2 = 0.0f, a3 = 0.0f;
#pragma unroll
        for (int k = 0; k < Kn; ++k) {
            const float wA = wv[k];          // ic = 0
            const float wB = wv[Kn + k];     // ic = 1
            a0 = fmaf(wA, xa[k + 2], a0); a0 = fmaf(wB, xc[k + 2], a0);
            a1 = fmaf(wA, xa[k + 3], a1); a1 = fmaf(wB, xc[k + 3], a1);
            a2 = fmaf(wA, xa[k + 4], a2); a2 = fmaf(wB, xc[k + 4], a2);
            a3 = fmaf(wA, xa[k + 5], a3); a3 = fmaf(wB, xc[k + 5], a3);
        }

        f32x4 v = {a0, a1, a2, a3};
        __builtin_nontemporal_store(v, reinterpret_cast<f32x4*>(yrow));

        xrow += ICn * Ln;
        yrow += SLICE;
    }
}

extern "C" void kernel_launch(void* const* d_in, const int* in_sizes, int n_in,
                              void* d_out, int out_size, void* d_ws, size_t ws_size,
                              hipStream_t stream) {
    const float* x  = (const float*)d_in[0];   // (B, IC, 1, L) f32
    const int*   z  = (const int*)d_in[1];     // (B, 5) i32
    const float* s  = (const float*)d_in[2];   // (B, 5) f32
    const float* w0 = (const float*)d_in[3];   // (OC, IC, 1, K) f32
    float* y = (float*)d_out;                  // (B, OC, 1, L) f32
    float* w = (float*)d_ws;                   // B*OC*IC*K = 20480 floats (80 KB)

    hipLaunchKernelGGL(wgen_kernel, dim3(Bn), dim3(64), 0, stream, z, s, w0, w);
    hipLaunchKernelGGL(conv_kernel, dim3(NBLK), dim3(TPB), 0, stream, x, w, y);
}